// Round 2
// 1920.923 us; speedup vs baseline: 1.3007x; 1.3007x over previous
//
#include <hip/hip_runtime.h>
#include <cstdint>

#define K_OFF 27
#define NDOWN 40000
#define NUP   160000
#define CDOWN 128
#define CSKIP 64
#define CCAT  192
#define COUT  96
#define TM    64
#define MT_D  5    // M-tiles per deconv block (625 = 125*5)
#define MT_C  10   // M-tiles per conv block   (2500 = 250*10)

typedef __bf16 bf16x8 __attribute__((ext_vector_type(8)));
typedef float f32x4 __attribute__((ext_vector_type(4)));

__device__ __forceinline__ unsigned short f2b(float f) {
    unsigned int u = __float_as_uint(f);
    u += 0x7FFFu + ((u >> 16) & 1u);           // round-to-nearest-even
    return (unsigned short)(u >> 16);
}
__device__ __forceinline__ unsigned int pk2(float a, float b) {
    return (unsigned)f2b(a) | ((unsigned)f2b(b) << 16);
}

// async global->LDS, 16B per lane, linear wave-uniform dest (rule #21: swizzle
// lives in the per-lane SOURCE address + the ds_read, LDS stays linear).
// Address-space casts via uintptr_t round-trip (CK amd_direct_load.hpp pattern;
// direct reinterpret_cast between address spaces is ill-formed in clang).
__device__ __forceinline__ void gll16(const void* gsrc, void* ldst) {
    auto g = reinterpret_cast<const __attribute__((address_space(1))) unsigned int*>(
        reinterpret_cast<uintptr_t>(gsrc));
    auto l = reinterpret_cast<__attribute__((address_space(3))) unsigned int*>(
        reinterpret_cast<uintptr_t>(ldst));
    __builtin_amdgcn_global_load_lds(g, l, 16, 0, 0);
}

// ---------------- precompute passes (memory-bound, run once) ----------------

// down f32 [NDOWN][128] -> bf16
__global__ void pack_down_kernel(const float* __restrict__ down,
                                 unsigned short* __restrict__ dbf) {
    int i = blockIdx.x * 256 + threadIdx.x;          // 8 elems per thread
    if (i >= NDOWN * CDOWN / 8) return;
    const float4* s = (const float4*)down + (long)i * 2;
    float4 v0 = s[0], v1 = s[1];
    uint4 o;
    o.x = pk2(v0.x, v0.y); o.y = pk2(v0.z, v0.w);
    o.z = pk2(v1.x, v1.y); o.w = pk2(v1.z, v1.w);
    ((uint4*)dbf)[i] = o;
}

// WdT[k][n][c] = bf16(Wd[k][c][n]);  WcT[k][n][c] = bf16(Wc[k][c][n])
__global__ void pack_w_kernel(const float* __restrict__ Wd, const float* __restrict__ Wc,
                              unsigned short* __restrict__ WdT, unsigned short* __restrict__ WcT) {
    int i = blockIdx.x * 256 + threadIdx.x;
    if (i < K_OFF * CDOWN * CDOWN) {
        int k = i / (CDOWN * CDOWN), rem = i % (CDOWN * CDOWN);
        int n = rem >> 7, c = rem & 127;
        WdT[i] = f2b(Wd[((long)k * CDOWN + c) * CDOWN + n]);
    }
    if (i < K_OFF * COUT * CCAT) {
        int k = i / (COUT * CCAT), rem = i % (COUT * CCAT);
        int n = rem / CCAT, c = rem % CCAT;
        WcT[i] = f2b(Wc[((long)k * CCAT + c) * COUT + n]);
    }
}

// cat[j][0:128] = bf16(relu(up[j])), cat[j][128:192] = bf16(skip[j])
__global__ void pack_cat_kernel(const float* __restrict__ up, const float* __restrict__ skip,
                                unsigned short* __restrict__ cat) {
    const int t = threadIdx.x;                       // 192 threads, 8 rows/block
    const int j = blockIdx.x * 8 + t / 24;
    const int s = t % 24;                            // 16B chunk within row
    const int e0 = s * 8;
    float4 v0, v1;
    if (e0 < CDOWN) {
        const float4* src = (const float4*)(up + (long)j * CDOWN + e0);
        v0 = src[0]; v1 = src[1];
        v0.x = fmaxf(v0.x, 0.f); v0.y = fmaxf(v0.y, 0.f);
        v0.z = fmaxf(v0.z, 0.f); v0.w = fmaxf(v0.w, 0.f);
        v1.x = fmaxf(v1.x, 0.f); v1.y = fmaxf(v1.y, 0.f);
        v1.z = fmaxf(v1.z, 0.f); v1.w = fmaxf(v1.w, 0.f);
    } else {
        const float4* src = (const float4*)(skip + (long)j * CSKIP + (e0 - CDOWN));
        v0 = src[0]; v1 = src[1];
    }
    uint4 o;
    o.x = pk2(v0.x, v0.y); o.y = pk2(v0.z, v0.w);
    o.z = pk2(v1.x, v1.y); o.w = pk2(v1.z, v1.w);
    ((uint4*)(cat + (long)j * CCAT))[s] = o;
}

// ---------------- fast deconv: bf16 gather via global_load_lds, B in regs ----------------
__global__ __launch_bounds__(256, 2)
void deconv_fast(const unsigned short* __restrict__ dbf,
                 const unsigned short* __restrict__ WdT,
                 const int* __restrict__ in_idx,
                 const int* __restrict__ out_idx,
                 float* __restrict__ up) {
    __shared__ __align__(1024) unsigned short sA[TM * CDOWN];   // 16 KB, linear, XOR-swizzled content

    const int segs = (NDOWN / TM) / MT_D;            // 125
    const int bk = blockIdx.x / segs;
    const int tile0 = (blockIdx.x % segs) * MT_D;
    const int t = threadIdx.x;
    const int wave = t >> 6, lane = t & 63;
    const int col = lane & 15, quad = lane >> 4;
    const int wm = wave & 1, wn = wave >> 1;         // 2x2 wave grid: 32 rows x 64 cols each

    // staging map: 4 gll16 per thread; row = chunk/16, swizzled source chunk
    int srow[4], soff[4];
#pragma unroll
    for (int i = 0; i < 4; i++) {
        int c = wave * 256 + i * 64 + lane;          // 1024 chunks total
        int r = c >> 4, cc = c & 15;
        srow[i] = r;
        soff[i] = (cc ^ (r & 7)) * 16;
    }

    // B fragments resident in VGPRs: 4 kk x 4 nt (64 VGPR), reused for MT_D tiles
    bf16x8 b[4][4];
    {
        const unsigned short* wb = WdT + (long)bk * CDOWN * CDOWN;
#pragma unroll
        for (int kk = 0; kk < 4; kk++)
#pragma unroll
            for (int nt = 0; nt < 4; nt++)
                b[kk][nt] = *(const bf16x8*)&wb[(wn * 64 + nt * 16 + col) * CDOWN + kk * 32 + quad * 8];
    }

    const long kBase = (long)bk * NDOWN;
    const char* sAc = (const char*)sA;

    for (int tt = 0; tt < MT_D; ++tt) {
        const int rowbase = (tile0 + tt) * TM;
#pragma unroll
        for (int i = 0; i < 4; i++) {
            const int j = in_idx[kBase + rowbase + srow[i]];
            gll16((const char*)dbf + (long)j * (CDOWN * 2) + soff[i],
                  (char*)sA + (wave * 4 + i) * 1024);
        }
        __syncthreads();                              // compiler drains vmcnt here

        f32x4 acc[2][4];
#pragma unroll
        for (int mi = 0; mi < 2; mi++)
#pragma unroll
            for (int nt = 0; nt < 4; nt++) acc[mi][nt] = (f32x4){0.f, 0.f, 0.f, 0.f};

#pragma unroll
        for (int kk = 0; kk < 4; kk++) {
            const int ch = kk * 4 + quad;
#pragma unroll
            for (int mi = 0; mi < 2; mi++) {
                const int row = wm * 32 + mi * 16 + col;
                bf16x8 a = *(const bf16x8*)(sAc + row * 256 + ((ch ^ (row & 7)) * 16));
#pragma unroll
                for (int nt = 0; nt < 4; nt++)
                    acc[mi][nt] = __builtin_amdgcn_mfma_f32_16x16x32_bf16(a, b[kk][nt], acc[mi][nt], 0, 0, 0);
            }
        }
        __syncthreads();                              // all waves done reading sA

#pragma unroll
        for (int mi = 0; mi < 2; mi++)
#pragma unroll
            for (int r = 0; r < 4; r++) {
                const int lrow = wm * 32 + mi * 16 + quad * 4 + r;
                const long ob = (long)out_idx[kBase + rowbase + lrow] * CDOWN;
#pragma unroll
                for (int nt = 0; nt < 4; nt++)
                    atomicAdd(&up[ob + wn * 64 + nt * 16 + col], acc[mi][nt][r]);
            }
    }
}

// ---------------- fast conv: gathers pre-packed bf16 cat, B in regs ----------------
__global__ __launch_bounds__(256, 2)
void conv_fast(const unsigned short* __restrict__ cat,
               const unsigned short* __restrict__ WcT,
               const int* __restrict__ in_idx,
               const int* __restrict__ out_idx,
               float* __restrict__ out) {
    __shared__ __align__(1024) unsigned short sA[TM * CCAT];    // 24.6 KB

    const int segs = (NUP / TM) / MT_C;              // 250
    const int bk = blockIdx.x / segs;
    const int tile0 = (blockIdx.x % segs) * MT_C;
    const int t = threadIdx.x;
    const int wave = t >> 6, lane = t & 63;
    const int col = lane & 15, quad = lane >> 4;
    const int wm = wave & 1, wn = wave >> 1;         // 2x2 wave grid: 32 rows x 48 cols each

    // staging map: 6 gll16 per thread; 24 chunks per 384B row
    int srow[6], soff[6];
#pragma unroll
    for (int i = 0; i < 6; i++) {
        int c = wave * 384 + i * 64 + lane;          // 1536 chunks total
        int r = c / 24, cc = c % 24;                 // XOR on low 3 bits keeps cc' < 24
        srow[i] = r;
        soff[i] = (cc ^ (r & 7)) * 16;
    }

    // B fragments resident: 6 kk x 3 nt (72 VGPR), reused for MT_C tiles
    bf16x8 b[6][3];
    {
        const unsigned short* wb = WcT + (long)bk * COUT * CCAT;
#pragma unroll
        for (int kk = 0; kk < 6; kk++)
#pragma unroll
            for (int nt = 0; nt < 3; nt++)
                b[kk][nt] = *(const bf16x8*)&wb[(wn * 48 + nt * 16 + col) * CCAT + kk * 32 + quad * 8];
    }

    const long kBase = (long)bk * NUP;
    const char* sAc = (const char*)sA;

    for (int tt = 0; tt < MT_C; ++tt) {
        const int rowbase = (tile0 + tt) * TM;
#pragma unroll
        for (int i = 0; i < 6; i++) {
            const int j = in_idx[kBase + rowbase + srow[i]];
            gll16((const char*)cat + (long)j * (CCAT * 2) + soff[i],
                  (char*)sA + (wave * 6 + i) * 1024);
        }
        __syncthreads();

        f32x4 acc[2][3];
#pragma unroll
        for (int mi = 0; mi < 2; mi++)
#pragma unroll
            for (int nt = 0; nt < 3; nt++) acc[mi][nt] = (f32x4){0.f, 0.f, 0.f, 0.f};

#pragma unroll
        for (int kk = 0; kk < 6; kk++) {
            const int ch = kk * 4 + quad;
#pragma unroll
            for (int mi = 0; mi < 2; mi++) {
                const int row = wm * 32 + mi * 16 + col;
                bf16x8 a = *(const bf16x8*)(sAc + row * 384 + ((ch ^ (row & 7)) * 16));
#pragma unroll
                for (int nt = 0; nt < 3; nt++)
                    acc[mi][nt] = __builtin_amdgcn_mfma_f32_16x16x32_bf16(a, b[kk][nt], acc[mi][nt], 0, 0, 0);
            }
        }
        __syncthreads();

#pragma unroll
        for (int mi = 0; mi < 2; mi++)
#pragma unroll
            for (int r = 0; r < 4; r++) {
                const int lrow = wm * 32 + mi * 16 + quad * 4 + r;
                const long ob = (long)out_idx[kBase + rowbase + lrow] * COUT;
#pragma unroll
                for (int nt = 0; nt < 3; nt++)
                    atomicAdd(&out[ob + wn * 48 + nt * 16 + col], acc[mi][nt][r]);
            }
    }
}

// ================= fallback path (previous verified kernels, ws too small) =================
#define SA1 136
#define SB1 136

__global__ __launch_bounds__(256, 2)
void deconv_kernel(const float* __restrict__ down,
                   const float* __restrict__ Wd,
                   const int* __restrict__ in_idx,
                   const int* __restrict__ out_idx,
                   float* __restrict__ up) {
    __shared__ __align__(16) unsigned short sA[TM * SA1];
    __shared__ __align__(16) unsigned short sB[CDOWN * SB1];
    __shared__ int sOut[TM];

    const int tiles = NDOWN / TM;
    const int bk = blockIdx.x / tiles;
    const int tile = blockIdx.x % tiles;
    const int t = threadIdx.x;
    const long kInBase = (long)bk * NDOWN + tile * TM;

    {
        const int r = t >> 2;
        const int c0 = (t & 3) * 32;
        const int j = in_idx[kInBase + r];
        const float* src = down + (long)j * CDOWN + c0;
        unsigned short* dst = sA + r * SA1 + c0;
        #pragma unroll
        for (int c = 0; c < 32; c += 4) {
            float4 v = *(const float4*)(src + c);
            *(unsigned int*)(dst + c)     = pk2(v.x, v.y);
            *(unsigned int*)(dst + c + 2) = pk2(v.z, v.w);
        }
    }
    {
        const float* wsrc = Wd + (long)bk * CDOWN * CDOWN;
        for (int idx = t; idx < CDOWN * CDOWN; idx += 256) {
            const int kk = idx >> 7;
            const int n  = idx & 127;
            sB[n * SB1 + kk] = f2b(wsrc[idx]);
        }
    }
    if (t < TM) sOut[t] = out_idx[kInBase + t];
    __syncthreads();

    const int wave = t >> 6;
    const int lane = t & 63;
    const int col  = lane & 15;
    const int quad = lane >> 4;
    const int mrow = wave * 16 + col;

    f32x4 acc[8];
    #pragma unroll
    for (int i = 0; i < 8; i++) acc[i] = (f32x4){0.f, 0.f, 0.f, 0.f};

    #pragma unroll
    for (int k0 = 0; k0 < CDOWN; k0 += 32) {
        const int koff = k0 + quad * 8;
        bf16x8 a = *(const bf16x8*)&sA[mrow * SA1 + koff];
        #pragma unroll
        for (int nt = 0; nt < 8; nt++) {
            bf16x8 bb = *(const bf16x8*)&sB[(nt * 16 + col) * SB1 + koff];
            acc[nt] = __builtin_amdgcn_mfma_f32_16x16x32_bf16(a, bb, acc[nt], 0, 0, 0);
        }
    }
    #pragma unroll
    for (int r = 0; r < 4; r++) {
        const int lrow = wave * 16 + quad * 4 + r;
        const long obase = (long)sOut[lrow] * CDOWN;
        #pragma unroll
        for (int nt = 0; nt < 8; nt++)
            atomicAdd(&up[obase + nt * 16 + col], acc[nt][r]);
    }
}

#define SA2 200
#define SB2 200

__global__ __launch_bounds__(256, 2)
void conv_kernel(const float* __restrict__ up,
                 const float* __restrict__ skip,
                 const float* __restrict__ Wc,
                 const int* __restrict__ in_idx,
                 const int* __restrict__ out_idx,
                 float* __restrict__ out) {
    __shared__ __align__(16) unsigned short sA[TM * SA2];
    __shared__ __align__(16) unsigned short sB[COUT * SB2];
    __shared__ int sOut[TM];

    const int tiles = NUP / TM;
    const int bk = blockIdx.x / tiles;
    const int tile = blockIdx.x % tiles;
    const int t = threadIdx.x;
    const long kInBase = (long)bk * NUP + tile * TM;

    {
        const int r = t >> 2;
        const int c0 = (t & 3) * 48;
        const int j = in_idx[kInBase + r];
        const float* uprow = up + (long)j * CDOWN;
        const float* skrow = skip + (long)j * CSKIP;
        unsigned short* dst = sA + r * SA2 + c0;
        #pragma unroll
        for (int c = 0; c < 48; c += 4) {
            const int gc = c0 + c;
            float4 v;
            if (gc < CDOWN) {
                v = *(const float4*)(uprow + gc);
                v.x = fmaxf(v.x, 0.f); v.y = fmaxf(v.y, 0.f);
                v.z = fmaxf(v.z, 0.f); v.w = fmaxf(v.w, 0.f);
            } else {
                v = *(const float4*)(skrow + (gc - CDOWN));
            }
            *(unsigned int*)(dst + c)     = pk2(v.x, v.y);
            *(unsigned int*)(dst + c + 2) = pk2(v.z, v.w);
        }
    }
    {
        const float* wsrc = Wc + (long)bk * CCAT * COUT;
        for (int idx = t; idx < CCAT * COUT; idx += 256) {
            const int kk = idx / COUT;
            const int n  = idx - kk * COUT;
            sB[n * SB2 + kk] = f2b(wsrc[idx]);
        }
    }
    if (t < TM) sOut[t] = out_idx[kInBase + t];
    __syncthreads();

    const int wave = t >> 6;
    const int lane = t & 63;
    const int col  = lane & 15;
    const int quad = lane >> 4;
    const int mrow = wave * 16 + col;

    f32x4 acc[6];
    #pragma unroll
    for (int i = 0; i < 6; i++) acc[i] = (f32x4){0.f, 0.f, 0.f, 0.f};

    #pragma unroll
    for (int k0 = 0; k0 < CCAT; k0 += 32) {
        const int koff = k0 + quad * 8;
        bf16x8 a = *(const bf16x8*)&sA[mrow * SA2 + koff];
        #pragma unroll
        for (int nt = 0; nt < 6; nt++) {
            bf16x8 bb = *(const bf16x8*)&sB[(nt * 16 + col) * SB2 + koff];
            acc[nt] = __builtin_amdgcn_mfma_f32_16x16x32_bf16(a, bb, acc[nt], 0, 0, 0);
        }
    }
    #pragma unroll
    for (int r = 0; r < 4; r++) {
        const int lrow = wave * 16 + quad * 4 + r;
        const long obase = (long)sOut[lrow] * COUT;
        #pragma unroll
        for (int nt = 0; nt < 6; nt++)
            atomicAdd(&out[obase + nt * 16 + col], acc[nt][r]);
    }
}

// ---------------- final ReLU on out ----------------
__global__ void relu_kernel(float* __restrict__ x, int n4) {
    int i = blockIdx.x * blockDim.x + threadIdx.x;
    if (i < n4) {
        float4 v = ((float4*)x)[i];
        v.x = fmaxf(v.x, 0.f); v.y = fmaxf(v.y, 0.f);
        v.z = fmaxf(v.z, 0.f); v.w = fmaxf(v.w, 0.f);
        ((float4*)x)[i] = v;
    }
}

extern "C" void kernel_launch(void* const* d_in, const int* in_sizes, int n_in,
                              void* d_out, int out_size, void* d_ws, size_t ws_size,
                              hipStream_t stream) {
    const float* skip   = (const float*)d_in[0];
    const float* down   = (const float*)d_in[1];
    const float* Wd     = (const float*)d_in[2];
    const float* Wc     = (const float*)d_in[3];
    const int* dc_in    = (const int*)d_in[4];
    const int* dc_out   = (const int*)d_in[5];
    const int* cv_in    = (const int*)d_in[6];
    const int* cv_out   = (const int*)d_in[7];
    float* out = (float*)d_out;
    float* up  = (float*)d_ws;                       // [NUP][CDOWN] f32 accumulator

    const size_t OFF_CAT = (size_t)NUP * CDOWN * 4;                    //  81,920,000
    const size_t OFF_DBF = OFF_CAT + (size_t)NUP * CCAT * 2;           // 143,360,000
    const size_t OFF_WDT = OFF_DBF + (size_t)NDOWN * CDOWN * 2;        // 153,600,000
    const size_t OFF_WCT = OFF_WDT + (size_t)K_OFF * CDOWN * CDOWN * 2;// 154,484,736
    const size_t WS_NEED = OFF_WCT + (size_t)K_OFF * COUT * CCAT * 2;  // 155,480,064

    hipMemsetAsync(up, 0, (size_t)NUP * CDOWN * sizeof(float), stream);
    hipMemsetAsync(out, 0, (size_t)out_size * sizeof(float), stream);

    if (ws_size >= WS_NEED) {
        unsigned short* catb = (unsigned short*)((char*)d_ws + OFF_CAT);
        unsigned short* dbf  = (unsigned short*)((char*)d_ws + OFF_DBF);
        unsigned short* WdT  = (unsigned short*)((char*)d_ws + OFF_WDT);
        unsigned short* WcT  = (unsigned short*)((char*)d_ws + OFF_WCT);

        pack_down_kernel<<<(NDOWN * CDOWN / 8 + 255) / 256, 256, 0, stream>>>(down, dbf);
        pack_w_kernel<<<(K_OFF * COUT * CCAT + 255) / 256, 256, 0, stream>>>(Wd, Wc, WdT, WcT);
        deconv_fast<<<K_OFF * ((NDOWN / TM) / MT_D), 256, 0, stream>>>(dbf, WdT, dc_in, dc_out, up);
        pack_cat_kernel<<<NUP / 8, 192, 0, stream>>>(up, skip, catb);
        conv_fast<<<K_OFF * ((NUP / TM) / MT_C), 256, 0, stream>>>(catb, WcT, cv_in, cv_out, out);
    } else {
        deconv_kernel<<<K_OFF * (NDOWN / TM), 256, 0, stream>>>(down, Wd, dc_in, dc_out, up);
        conv_kernel<<<K_OFF * (NUP / TM), 256, 0, stream>>>(up, skip, Wc, cv_in, cv_out, out);
    }
    relu_kernel<<<(out_size / 4 + 255) / 256, 256, 0, stream>>>(out, out_size / 4);
}